// Round 8
// baseline (4757.355 us; speedup 1.0000x reference)
//
#include <hip/hip_runtime.h>
#include <cstdint>
#include <cstddef>

#define D_MOD 512
#define TH3   1536
#define CLS   8000
#define MAXLEN 80
#define B_SZ  128
#define T_LEN 128
#define NK0   16   // 512/32 k-chunks
#define EGI_ROWS 8000
#define HPK_ELEMS 65536          // 128 rows x 512 k, packed layout, per step
#define CTR_WORDS (MAXLEN * 32)  // per-step: [t*32]=ticket, [t*32+16]=done

typedef __attribute__((ext_vector_type(8))) __bf16 bf16x8;
typedef __attribute__((ext_vector_type(8))) unsigned short u16x8;
typedef __attribute__((ext_vector_type(4))) float f32x4;

// ---------------------------------------------------------------------------
// helpers
// ---------------------------------------------------------------------------
__device__ __forceinline__ unsigned short f2bf(float x) {
    unsigned u = __float_as_uint(x);
    unsigned r = ((u >> 16) & 1u) + 0x7fffu;   // RNE
    return (unsigned short)((u + r) >> 16);
}
__device__ __forceinline__ float bf2f(unsigned short h) {
    return __uint_as_float(((unsigned)h) << 16);
}
__device__ __forceinline__ f32x4 mfma16(u16x8 a, u16x8 b, f32x4 c) {
    return __builtin_amdgcn_mfma_f32_16x16x32_bf16(
        __builtin_bit_cast(bf16x8, a), __builtin_bit_cast(bf16x8, b), c, 0, 0, 0);
}
__device__ __forceinline__ void conv8(const float* __restrict__ p, u16x8& hi, u16x8& lo) {
    float4 f0 = *(const float4*)p;
    float4 f1 = *(const float4*)(p + 4);
    float fs[8] = {f0.x, f0.y, f0.z, f0.w, f1.x, f1.y, f1.z, f1.w};
    #pragma unroll
    for (int j = 0; j < 8; ++j) {
        unsigned short h = f2bf(fs[j]);
        hi[j] = h;
        lo[j] = f2bf(fs[j] - bf2f(h));
    }
}
__device__ __forceinline__ unsigned long long packkey(float v, int n) {
    unsigned u = __float_as_uint(v);
    u = (u & 0x80000000u) ? ~u : (u | 0x80000000u);
    return ((unsigned long long)u << 32) | (unsigned)(~(unsigned)n);
}
__device__ __forceinline__ unsigned long long shfl_xor_u64(unsigned long long x, int mask) {
    unsigned lo = (unsigned)x, hi = (unsigned)(x >> 32);
    lo = __shfl_xor(lo, mask, 16);
    hi = __shfl_xor(hi, mask, 16);
    return ((unsigned long long)hi << 32) | lo;
}
// fragment-major packed offset for (row n, col k), rows grouped in tiles of 16
__device__ __forceinline__ size_t pk_off(int n, int k) {
    int tile = n >> 4, lr = n & 15, k0i = k >> 5, lk = (k >> 3) & 3, e = k & 7;
    return ((size_t)(tile * NK0 + k0i) * 64 + (lk * 16 + lr)) * 8 + e;
}

// ---------------------------------------------------------------------------
// fp32 -> bf16 hi/lo PACKED converter. total4 = R*128 groups of 4 elems.
// ---------------------------------------------------------------------------
__global__ __launch_bounds__(256) void cvt2p_kernel(
    const float* __restrict__ s1, const float* __restrict__ s2, int ld,
    long total4, unsigned short* __restrict__ hi, unsigned short* __restrict__ lo)
{
    long i4 = (long)blockIdx.x * 256 + threadIdx.x;
    if (i4 >= total4) return;
    long r = i4 >> 7;
    int c = (int)(i4 & 127) * 4;
    float4 a = *(const float4*)(s1 + r * (long)ld + c);
    if (s2) {
        float4 b = *(const float4*)(s2 + r * (long)ld + c);
        a.x += b.x; a.y += b.y; a.z += b.z; a.w += b.w;
    }
    float xs[4] = {a.x, a.y, a.z, a.w};
    unsigned short hs[4], ls[4];
    #pragma unroll
    for (int j = 0; j < 4; ++j) {
        hs[j] = f2bf(xs[j]);
        ls[j] = f2bf(xs[j] - bf2f(hs[j]));
    }
    size_t o = pk_off((int)r, c);
    *(ushort4*)(hi + o) = make_ushort4(hs[0], hs[1], hs[2], hs[3]);
    *(ushort4*)(lo + o) = make_ushort4(ls[0], ls[1], ls[2], ls[3]);
}

// ---------------------------------------------------------------------------
// K-split MFMA GEMM body (r3-identical), 8 waves = NS n-subtiles x KS
// k-slices. Wave tile: 16m x 32n x (512/KS)k. LDS tree-reduce via red
// ((KS-1)*NS*576 floats). GATHER_CONV + gslot==nullptr -> direct row.
// ---------------------------------------------------------------------------
template<bool GATHER_CONV, bool CONVB, bool ADD2D, bool ARGMAX, int NS, int KS>
__device__ __forceinline__ void gemm_ks2(
    float* __restrict__ red,
    const unsigned short* __restrict__ Ahi, const unsigned short* __restrict__ Alo,
    const float* __restrict__ Afp, const unsigned long long* __restrict__ gslot,
    const unsigned short* __restrict__ Bhi, const unsigned short* __restrict__ Blo,
    const float* __restrict__ Bfp,
    const float* __restrict__ bias, const float* __restrict__ D2,
    float* __restrict__ C, int ldc,
    unsigned long long* __restrict__ aslot, int bx, int by)
{
    static_assert(NS * KS == 8, "8 waves per block");
    const int tid = threadIdx.x;
    const int w = tid >> 6, lane = tid & 63;
    const int lr = lane & 15, lk = lane >> 4;
    const int ns = w % NS, ks = w / NS;
    const int m0 = by * 16;
    const int n0 = (bx * NS + ns) * 32;
    const int tA = by;
    const int tB0 = n0 >> 4, tB1 = tB0 + 1;

    const float* paf = nullptr;
    if constexpr (GATHER_CONV) {
        int g = gslot ? (int)(~(unsigned)gslot[m0 + lr]) : (m0 + lr);
        paf = Afp + (size_t)g * D_MOD + lk * 8;
    }
    const float *pb0f = nullptr, *pb1f = nullptr;
    if constexpr (CONVB) {
        pb0f = Bfp + (size_t)(n0 + lr) * D_MOD + lk * 8;
        pb1f = Bfp + (size_t)(n0 + 16 + lr) * D_MOD + lk * 8;
    }

    f32x4 acc0 = (f32x4){0.f, 0.f, 0.f, 0.f};
    f32x4 acc1 = (f32x4){0.f, 0.f, 0.f, 0.f};

    const int kBeg = ks * (NK0 / KS), kEnd = kBeg + (NK0 / KS);
    for (int k0i = kBeg; k0i < kEnd; ++k0i) {
        u16x8 ah, al, b0h, b0l, b1h, b1l;
        if constexpr (GATHER_CONV) {
            conv8(paf + k0i * 32, ah, al);
        } else {
            size_t oA = ((size_t)(tA * NK0 + k0i) * 64 + lane) * 8;
            ah = *(const u16x8*)(Ahi + oA); al = *(const u16x8*)(Alo + oA);
        }
        if constexpr (CONVB) {
            conv8(pb0f + k0i * 32, b0h, b0l);
            conv8(pb1f + k0i * 32, b1h, b1l);
        } else {
            size_t oB0 = ((size_t)(tB0 * NK0 + k0i) * 64 + lane) * 8;
            size_t oB1 = ((size_t)(tB1 * NK0 + k0i) * 64 + lane) * 8;
            b0h = *(const u16x8*)(Bhi + oB0); b0l = *(const u16x8*)(Blo + oB0);
            b1h = *(const u16x8*)(Bhi + oB1); b1l = *(const u16x8*)(Blo + oB1);
        }
        acc0 = mfma16(ah, b0h, acc0);
        acc0 = mfma16(ah, b0l, acc0);
        acc0 = mfma16(al, b0h, acc0);
        acc1 = mfma16(ah, b1h, acc1);
        acc1 = mfma16(ah, b1l, acc1);
        acc1 = mfma16(al, b1h, acc1);
    }

    float af[8];
    #pragma unroll
    for (int i = 0; i < 4; ++i) { af[i] = acc0[i]; af[4 + i] = acc1[i]; }

    if (ks > 0) {
        const int slot = (ks - 1) * NS + ns;
        #pragma unroll
        for (int i = 0; i < 8; ++i) red[slot * 576 + lane * 9 + i] = af[i];
    }
    __syncthreads();
    if (ks == 0) {
        #pragma unroll
        for (int j = 1; j < KS; ++j) {
            const int slot = (j - 1) * NS + ns;
            #pragma unroll
            for (int i = 0; i < 8; ++i) af[i] += red[slot * 576 + lane * 9 + i];
        }
        #pragma unroll
        for (int r = 0; r < 4; ++r) {
            const int row = m0 + lk * 4 + r;
            unsigned long long kmax = 0ull;
            #pragma unroll
            for (int ni = 0; ni < 2; ++ni) {
                const int col = n0 + ni * 16 + lr;
                float val = af[ni * 4 + r];
                if (bias) val += bias[col];
                if constexpr (ADD2D) val += D2[(size_t)row * ldc + col];
                C[(size_t)row * ldc + col] = val;
                if constexpr (ARGMAX) {
                    unsigned long long k = packkey(val, col);
                    if (k > kmax) kmax = k;
                }
            }
            if constexpr (ARGMAX) {
                #pragma unroll
                for (int off = 1; off < 16; off <<= 1) {
                    unsigned long long o = shfl_xor_u64(kmax, off);
                    if (o > kmax) kmax = o;
                }
                if (lr == 0) atomicMax(&aslot[row], kmax);
            }
        }
    }
}

// XCD-pinned remap: physical block p (round-robin p%8 over XCDs) ->
// (bx, by) with all 8 by-sharers of a bx consecutive on ONE XCD.
template<int G>
__device__ __forceinline__ bool xcd_map(int p, int& bx, int& by) {
    int x = p & 7, s = p >> 3;
    by = s & 7;
    bx = x * G + (s >> 3);
    return true;
}

// ---------------------------------------------------------------------------
// GRU job (EGIB): gi = Egi[sel] + gc gather; bitwise-identical math to the
// fallback (gemm + gc) then + gh path. Plain-store variant (cross-kernel).
// ---------------------------------------------------------------------------
__device__ __forceinline__ void gru_job_egi(
    int b, const float* __restrict__ gh, const float* __restrict__ Egi,
    const float* __restrict__ gc, const unsigned long long* __restrict__ sPrev,
    const float* __restrict__ hPrev, float* __restrict__ hCur,
    unsigned short* __restrict__ hHiC, unsigned short* __restrict__ hLoC,
    unsigned long long* __restrict__ slotCur)
{
    const int k = threadIdx.x;
    const int sel = (int)(~(unsigned)sPrev[b]);
    const float* gib = Egi + (size_t)sel * TH3;
    const float* gcb = gc + (size_t)b * TH3;
    const float* ghb = gh + (size_t)b * TH3;
    float gi0 = gib[k] + gcb[k];
    float gi1 = gib[k + 512] + gcb[k + 512];
    float gi2 = gib[k + 1024] + gcb[k + 1024];
    float r = 1.f / (1.f + expf(-(gi0 + ghb[k])));
    float z = 1.f / (1.f + expf(-(gi1 + ghb[k + 512])));
    float n = tanhf(gi2 + r * ghb[k + 1024]);
    float h = hPrev[(size_t)b * D_MOD + k];
    float hv = (1.f - z) * n + z * h;
    hCur[(size_t)b * D_MOD + k] = hv;
    unsigned short hh = f2bf(hv);
    size_t o = pk_off(b, k);
    hHiC[o] = hh;
    hLoC[o] = f2bf(hv - bf2f(hh));
    if (k == 0) slotCur[b] = 0ull;
}

// ---------------------------------------------------------------------------
// FUSED step kernel (1 launch/step). Ticket head: first 128 ticket-takers
// (running blocks by construction -> deadlock-free) each compute one GRU row,
// writing packed h via WRITE-THROUGH atomic stores into a FRESH per-step
// buffer (never L2-cached before within a replay -> readers' plain loads
// cannot hit stale lines; they miss to the memory-side Infinity Cache where
// the atomics landed). vmcnt drained by __syncthreads before done++. Then all
// 1408 blocks spin (relaxed, off critical path) and run the r3-identical
// GEMMs with PLAIN cached A loads: p<1024 cls(t), p>=1024 gh(t+1).
// gh buffer hazard-free: gru reads gh(t) strictly before done++, gh(t+1)
// writes strictly after done==128.
// ---------------------------------------------------------------------------
__global__ __launch_bounds__(512) void fused_step_kernel(
    const unsigned short* __restrict__ WhhHi, const unsigned short* __restrict__ WhhLo,
    const float* __restrict__ b_hh,
    const unsigned short* __restrict__ WcHi, const unsigned short* __restrict__ WcLo,
    const float* __restrict__ bc,
    const float* __restrict__ Egi, const float* __restrict__ gc,
    float* __restrict__ gh,
    const unsigned long long* __restrict__ sPrev, unsigned long long* __restrict__ sCur,
    const float* __restrict__ hPrevF, float* __restrict__ hCurF,
    unsigned short* __restrict__ hPkHi, unsigned short* __restrict__ hPkLo,
    float* __restrict__ out, unsigned* __restrict__ ctr)
{
    __shared__ float red[7 * 576];
    __shared__ unsigned tk_sh;
    const int tid = threadIdx.x;
    unsigned* done = ctr + 16;

    if (tid == 0)
        tk_sh = __hip_atomic_fetch_add(ctr, 1u, __ATOMIC_RELAXED, __HIP_MEMORY_SCOPE_AGENT);
    __syncthreads();
    const unsigned tk = tk_sh;

    if (tk < (unsigned)B_SZ) {
        const int b = (int)tk, k = tid;
        const int sel = (int)(~(unsigned)sPrev[b]);
        const float* gib = Egi + (size_t)sel * TH3;
        const float* gcb = gc + (size_t)b * TH3;
        const float* ghb = gh + (size_t)b * TH3;
        float gi0 = gib[k] + gcb[k];
        float gi1 = gib[k + 512] + gcb[k + 512];
        float gi2 = gib[k + 1024] + gcb[k + 1024];
        float r = 1.f / (1.f + expf(-(gi0 + ghb[k])));
        float z = 1.f / (1.f + expf(-(gi1 + ghb[k + 512])));
        float n = tanhf(gi2 + r * ghb[k + 1024]);
        float h = hPrevF[(size_t)b * D_MOD + k];
        float hv = (1.f - z) * n + z * h;
        hCurF[(size_t)b * D_MOD + k] = hv;           // plain: next kernel only
        unsigned short hh = f2bf(hv);
        unsigned short ll = f2bf(hv - bf2f(hh));
        unsigned hh_u = hh, ll_u = ll;
        unsigned hh_n = __shfl_down(hh_u, 1);
        unsigned ll_n = __shfl_down(ll_u, 1);
        if ((k & 1) == 0) {                          // 4B write-through pairs
            size_t o = pk_off(b, k);                 // even e -> 4B aligned
            __hip_atomic_store((unsigned*)(hPkHi + o), hh_u | (hh_n << 16),
                               __ATOMIC_RELAXED, __HIP_MEMORY_SCOPE_AGENT);
            __hip_atomic_store((unsigned*)(hPkLo + o), ll_u | (ll_n << 16),
                               __ATOMIC_RELAXED, __HIP_MEMORY_SCOPE_AGENT);
        }
        if (k == 0)
            __hip_atomic_store(&sCur[b], 0ull, __ATOMIC_RELAXED, __HIP_MEMORY_SCOPE_AGENT);
        __syncthreads();                             // every wave drains vmcnt
        if (tid == 0)
            __hip_atomic_fetch_add(done, 1u, __ATOMIC_RELAXED, __HIP_MEMORY_SCOPE_AGENT);
    }

    if (tid == 0) {
        while (__hip_atomic_load(done, __ATOMIC_RELAXED, __HIP_MEMORY_SCOPE_AGENT)
               < (unsigned)B_SZ)
            __builtin_amdgcn_s_sleep(8);
    }
    __syncthreads();
    asm volatile("" ::: "memory");

    const int p = (int)blockIdx.x;
    if (p < 1024) {
        int bx, by;
        xcd_map<16>(p, bx, by);
        if (bx < 125)
            gemm_ks2<false, false, false, true, 2, 4>(red, hPkHi, hPkLo, nullptr, nullptr,
                WcHi, WcLo, nullptr, bc, nullptr, out, CLS, sCur, bx, by);
    } else {
        int bx, by;
        xcd_map<6>(p - 1024, bx, by);
        gemm_ks2<false, false, false, false, 1, 8>(red, hPkHi, hPkLo, nullptr, nullptr,
            WhhHi, WhhLo, nullptr, b_hh, nullptr, gh, TH3, nullptr, bx, by);
    }
}

// ---------------------------------------------------------------------------
// one-time prologue (EGIB only): Egi = emb @ Wiha^T, rows 0..7999.
// ---------------------------------------------------------------------------
__global__ __launch_bounds__(512) void egi_kernel(
    const float* __restrict__ emb,
    const unsigned short* __restrict__ WihaHi, const unsigned short* __restrict__ WihaLo,
    float* __restrict__ Egi)
{
    __shared__ float red[7 * 576];
    int p = blockIdx.x;
    int x = p & 7, s = p >> 3;
    int by = s % 500, bx = x * 6 + s / 500;
    gemm_ks2<true, false, false, false, 1, 8>(red, nullptr, nullptr, emb, nullptr,
        WihaHi, WihaLo, nullptr, nullptr, nullptr, Egi, TH3, nullptr, bx, by);
}

// gh = h @ Whh^T + b_hh only, grid 384 x 512thr (prologue gh(0))
__global__ __launch_bounds__(512) void gh_kernel(
    const unsigned short* __restrict__ hHi, const unsigned short* __restrict__ hLo,
    const unsigned short* __restrict__ WhhHi, const unsigned short* __restrict__ WhhLo,
    const float* __restrict__ b_hh, float* __restrict__ gh)
{
    __shared__ float red[7 * 576];
    int bx, by;
    xcd_map<6>(blockIdx.x, bx, by);
    gemm_ks2<false, false, false, false, 1, 8>(red, hHi, hLo, nullptr, nullptr,
        WhhHi, WhhLo, nullptr, b_hh, nullptr, gh, TH3, nullptr, bx, by);
}

// ---------------------------------------------------------------------------
// MERGED step node (fallback r3): cls(t) [p<1024] || gh(t+1) [p>=1024].
// ---------------------------------------------------------------------------
template<bool CONVB>
__global__ __launch_bounds__(512) void cls_gh_kernel(
    const unsigned short* __restrict__ hHi, const unsigned short* __restrict__ hLo,
    const unsigned short* __restrict__ WcHi, const unsigned short* __restrict__ WcLo,
    const float* __restrict__ Wc, const float* __restrict__ bc,
    float* __restrict__ C, unsigned long long* __restrict__ aslot,
    const unsigned short* __restrict__ WhhHi, const unsigned short* __restrict__ WhhLo,
    const float* __restrict__ b_hh, float* __restrict__ gh)
{
    __shared__ float red[7 * 576];
    const int p = blockIdx.x;
    if (p < 1024) {
        int bx, by;
        xcd_map<16>(p, bx, by);
        if (bx >= 125) return;
        gemm_ks2<false, CONVB, false, true, 2, 4>(red, hHi, hLo, nullptr, nullptr,
            WcHi, WcLo, Wc, bc, nullptr, C, CLS, aslot, bx, by);
    } else {
        int bx, by;
        xcd_map<6>(p - 1024, bx, by);
        gemm_ks2<false, false, false, false, 1, 8>(red, hHi, hLo, nullptr, nullptr,
            WhhHi, WhhLo, nullptr, b_hh, nullptr, gh, TH3, nullptr, bx, by);
    }
}

// gh (p<384) and gi (p>=384), grid 768 x 512thr (fallback step node 1)
__global__ __launch_bounds__(512) void step_dual_kernel(
    const unsigned short* __restrict__ hHi, const unsigned short* __restrict__ hLo,
    const unsigned short* __restrict__ WhhHi, const unsigned short* __restrict__ WhhLo,
    const float* __restrict__ b_hh,
    const float* __restrict__ emb, const unsigned long long* __restrict__ sPrev,
    const unsigned short* __restrict__ WihaHi, const unsigned short* __restrict__ WihaLo,
    const float* __restrict__ gc,
    float* __restrict__ gh, float* __restrict__ gi)
{
    __shared__ float red[7 * 576];
    int p = blockIdx.x;
    const int z = (p >= 384);
    p -= z * 384;
    int bx, by;
    xcd_map<6>(p, bx, by);
    if (z == 0)
        gemm_ks2<false, false, false, false, 1, 8>(red, hHi, hLo, nullptr, nullptr,
            WhhHi, WhhLo, nullptr, b_hh, nullptr, gh, TH3, nullptr, bx, by);
    else
        gemm_ks2<true, false, true, false, 1, 8>(red, nullptr, nullptr, emb, sPrev,
            WihaHi, WihaLo, nullptr, nullptr, gc, gi, TH3, nullptr, bx, by);
}

// gc = c @ Wihb^T + b_ih, grid 384 x 512thr
__global__ __launch_bounds__(512) void gemm128_kernel(
    const unsigned short* __restrict__ Ahi, const unsigned short* __restrict__ Alo,
    const unsigned short* __restrict__ Bhi, const unsigned short* __restrict__ Blo,
    const float* __restrict__ bias, float* __restrict__ C)
{
    __shared__ float red[7 * 576];
    int bx, by;
    xcd_map<6>(blockIdx.x, bx, by);
    gemm_ks2<false, false, false, false, 1, 8>(red, Ahi, Alo, nullptr, nullptr,
        Bhi, Blo, nullptr, bias, nullptr, C, TH3, nullptr, bx, by);
}

// classifier standalone (fallback): grid 1024 x 512thr
template<bool CONVB>
__global__ __launch_bounds__(512) void cls_kernel(
    const unsigned short* __restrict__ hHi, const unsigned short* __restrict__ hLo,
    const unsigned short* __restrict__ WcHi, const unsigned short* __restrict__ WcLo,
    const float* __restrict__ Wc, const float* __restrict__ bc,
    float* __restrict__ C, unsigned long long* __restrict__ aslot)
{
    __shared__ float red[3 * 2 * 576];
    int bx, by;
    xcd_map<16>(blockIdx.x, bx, by);
    if (bx >= 125) return;
    gemm_ks2<false, CONVB, false, true, 2, 4>(red, hHi, hLo, nullptr, nullptr,
        WcHi, WcLo, Wc, bc, nullptr, C, CLS, aslot, bx, by);
}

// ---------------------------------------------------------------------------
// attention scores e[m] = v . tanh(inp_row @ Wqk^T + bq+bk), packed B.
// ---------------------------------------------------------------------------
__global__ __launch_bounds__(256) void attn_e_mfma(
    const float* __restrict__ inp,
    const unsigned short* __restrict__ WqkHi, const unsigned short* __restrict__ WqkLo,
    const float* __restrict__ bq, const float* __restrict__ bk,
    const float* __restrict__ v, float* __restrict__ e)
{
    __shared__ __align__(16) unsigned short Ah[32][40];
    __shared__ __align__(16) unsigned short Al[32][40];
    __shared__ float red[4][32];
    const int tid = threadIdx.x, w = tid >> 6, lane = tid & 63;
    const int lr = lane & 15, lk = lane >> 4;
    const int m0 = blockIdx.x * 32;
    const int srow = tid >> 3, scol = (tid & 7) * 4;

    f32x4 acc[2][8];
    #pragma unroll
    for (int i = 0; i < 2; ++i)
        #pragma unroll
        for (int j = 0; j < 8; ++j) acc[i][j] = (f32x4){0.f, 0.f, 0.f, 0.f};

    for (int k0i = 0; k0i < NK0; ++k0i) {
        float4 x = *(const float4*)(inp + (size_t)(m0 + srow) * D_MOD + k0i * 32 + scol);
        float xs[4] = {x.x, x.y, x.z, x.w};
        #pragma unroll
        for (int j = 0; j < 4; ++j) {
            unsigned short h = f2bf(xs[j]);
            Ah[srow][scol + j] = h;
            Al[srow][scol + j] = f2bf(xs[j] - bf2f(h));
        }
        __syncthreads();
        u16x8 a[2][2];
        #pragma unroll
        for (int mi = 0; mi < 2; ++mi) {
            a[mi][0] = *(const u16x8*)&Ah[mi * 16 + lr][lk * 8];
            a[mi][1] = *(const u16x8*)&Al[mi * 16 + lr][lk * 8];
        }
        #pragma unroll
        for (int nf = 0; nf < 8; ++nf) {
            const int tile = w * 8 + nf;
            size_t ob = ((size_t)(tile * NK0 + k0i) * 64 + lane) * 8;
            u16x8 bh = *(const u16x8*)(WqkHi + ob);
            u16x8 bl = *(const u16x8*)(WqkLo + ob);
            #pragma unroll
            for (int mi = 0; mi < 2; ++mi) {
                acc[mi][nf] = mfma16(a[mi][0], bh, acc[mi][nf]);
                acc[mi][nf] = mfma16(a[mi][0], bl, acc[mi][nf]);
                acc[mi][nf] = mfma16(a[mi][1], bh, acc[mi][nf]);
            }
        }
        __syncthreads();
    }

    float ep[2][4];
    #pragma unroll
    for (int mi = 0; mi < 2; ++mi)
        #pragma unroll
        for (int r = 0; r < 4; ++r) ep[mi][r] = 0.f;
    #pragma unroll
    for (int nf = 0; nf < 8; ++nf) {
        const int col = w * 128 + nf * 16 + lr;
        const float bb = bq[col] + bk[col];
        const float vv = v[col];
        #pragma unroll
        for (int mi = 0; mi < 2; ++mi)
            #pragma unroll
            for (int r = 0; r < 4; ++r)
                ep[mi][r] += vv * tanhf(acc[mi][nf][r] + bb);
    }
    #pragma unroll
    for (int mi = 0; mi < 2; ++mi)
        #pragma unroll
        for (int r = 0; r < 4; ++r) {
            float s = ep[mi][r];
            #pragma unroll
            for (int off = 1; off < 16; off <<= 1) s += __shfl_xor(s, off, 16);
            if (lr == 0) red[w][mi * 16 + lk * 4 + r] = s;
        }
    __syncthreads();
    if (tid < 32) e[m0 + tid] = red[0][tid] + red[1][tid] + red[2][tid] + red[3][tid];
}

// ---------------------------------------------------------------------------
// softmax over T per batch col; context c and h0 emitted PACKED hi/lo;
// h0 also fp32 row-major; slot init; step counters zeroed (replay-safe).
// grid 128, block 256.
// ---------------------------------------------------------------------------
__global__ __launch_bounds__(256) void softmax_ctx_kernel(
    const float* __restrict__ inp, const float* __restrict__ e,
    unsigned short* __restrict__ cHi, unsigned short* __restrict__ cLo,
    float* __restrict__ h1, unsigned short* __restrict__ h1Hi, unsigned short* __restrict__ h1Lo,
    unsigned long long* __restrict__ slots, unsigned* __restrict__ ctrs)
{
    __shared__ float att[T_LEN];
    __shared__ float red;
    const int b = blockIdx.x, tid = threadIdx.x;
    if (b == 0)
        for (int i = tid; i < CTR_WORDS; i += 256) ctrs[i] = 0u;
    float val = -1e30f;
    if (tid < T_LEN) { val = e[(size_t)tid * B_SZ + b]; att[tid] = val; }
    __syncthreads();
    if (tid < 64) {
        float m = fmaxf(att[tid], att[tid + 64]);
        #pragma unroll
        for (int off = 32; off; off >>= 1) m = fmaxf(m, __shfl_xor(m, off));
        if (tid == 0) red = m;
    }
    __syncthreads();
    const float mx = red;
    __syncthreads();
    if (tid < T_LEN) att[tid] = expf(val - mx);
    __syncthreads();
    if (tid < 64) {
        float s = att[tid] + att[tid + 64];
        #pragma unroll
        for (int off = 32; off; off >>= 1) s += __shfl_xor(s, off);
        if (tid == 0) red = s;
    }
    __syncthreads();
    const float inv = 1.f / red;

    const int d0 = tid * 2;
    float ax = 0.f, ay = 0.f;
    for (int t = 0; t < T_LEN; ++t) {
        float a = att[t];
        float2 x = *(const float2*)(inp + ((size_t)t * B_SZ + b) * D_MOD + d0);
        ax += a * x.x; ay += a * x.y;
        if (t == 0) {
            *(float2*)(h1 + (size_t)b * D_MOD + d0) = x;
            unsigned short hx = f2bf(x.x), hy = f2bf(x.y);
            h1Hi[pk_off(b, d0)]     = hx;
            h1Hi[pk_off(b, d0 + 1)] = hy;
            h1Lo[pk_off(b, d0)]     = f2bf(x.x - bf2f(hx));
            h1Lo[pk_off(b, d0 + 1)] = f2bf(x.y - bf2f(hy));
        }
    }
    ax *= inv; ay *= inv;
    unsigned short cx = f2bf(ax), cy = f2bf(ay);
    cHi[pk_off(b, d0)]     = cx;
    cHi[pk_off(b, d0 + 1)] = cy;
    cLo[pk_off(b, d0)]     = f2bf(ax - bf2f(cx));
    cLo[pk_off(b, d0 + 1)] = f2bf(ay - bf2f(cy));
    if (tid == 0) {
        slots[b] = 0ull;
        slots[B_SZ + b] = 0x00000000FFFFFFFFull;   // idx 0 (SOS)
    }
}

// ---------------------------------------------------------------------------
// GRU combine kernels (fallbacks)
// ---------------------------------------------------------------------------
__global__ __launch_bounds__(512) void gru_combine(
    const float* __restrict__ gh, const float* __restrict__ gi,
    const float* __restrict__ hPrev, float* __restrict__ hCur,
    unsigned short* __restrict__ hHiC, unsigned short* __restrict__ hLoC,
    unsigned long long* __restrict__ slotCur)
{
    const int b = blockIdx.x, k = threadIdx.x;
    const float* gib = gi + (size_t)b * TH3;
    const float* ghb = gh + (size_t)b * TH3;
    float r = 1.f / (1.f + expf(-(gib[k] + ghb[k])));
    float z = 1.f / (1.f + expf(-(gib[k + 512] + ghb[k + 512])));
    float n = tanhf(gib[k + 1024] + r * ghb[k + 1024]);
    float h = hPrev[(size_t)b * D_MOD + k];
    float hv = (1.f - z) * n + z * h;
    hCur[(size_t)b * D_MOD + k] = hv;
    unsigned short hh = f2bf(hv);
    size_t o = pk_off(b, k);
    hHiC[o] = hh;
    hLoC[o] = f2bf(hv - bf2f(hh));
    if (k == 0) slotCur[b] = 0ull;
}

__global__ __launch_bounds__(512) void gru_combine_egi(
    const float* __restrict__ gh, const float* __restrict__ Egi,
    const float* __restrict__ gc, const unsigned long long* __restrict__ sPrev,
    const float* __restrict__ hPrev, float* __restrict__ hCur,
    unsigned short* __restrict__ hHiC, unsigned short* __restrict__ hLoC,
    unsigned long long* __restrict__ slotCur)
{
    gru_job_egi(blockIdx.x, gh, Egi, gc, sPrev, hPrev, hCur, hHiC, hLoC, slotCur);
}

// ---------------------------------------------------------------------------
// launch
// ---------------------------------------------------------------------------
extern "C" void kernel_launch(void* const* d_in, const int* in_sizes, int n_in,
                              void* d_out, int out_size, void* d_ws, size_t ws_size,
                              hipStream_t stream)
{
    const float* inp  = (const float*)d_in[0];
    const float* Wq   = (const float*)d_in[1];
    const float* bq   = (const float*)d_in[2];
    const float* Wk   = (const float*)d_in[3];
    const float* bk   = (const float*)d_in[4];
    const float* v    = (const float*)d_in[5];
    const float* W_ih = (const float*)d_in[6];
    const float* b_ih = (const float*)d_in[7];
    const float* W_hh = (const float*)d_in[8];
    const float* b_hh = (const float*)d_in[9];
    const float* emb  = (const float*)d_in[10];
    const float* Wc   = (const float*)d_in[11];
    const float* bc   = (const float*)d_in[12];
    float* out = (float*)d_out;

    char* base = (char*)d_ws;
    size_t off = 0;
    auto alloc = [&](size_t bytes) -> char* {
        char* q = base + off;
        off += (bytes + 255) & ~(size_t)255;
        return q;
    };
    typedef unsigned short us;
    us* WqkHi  = (us*)alloc(512 * 512 * 2);
    us* WqkLo  = (us*)alloc(512 * 512 * 2);
    us* WhhHi  = (us*)alloc((size_t)TH3 * 512 * 2);
    us* WhhLo  = (us*)alloc((size_t)TH3 * 512 * 2);
    us* WihaHi = (us*)alloc((size_t)TH3 * 512 * 2);
    us* WihaLo = (us*)alloc((size_t)TH3 * 512 * 2);
    us* WihbHi = (us*)alloc((size_t)TH3 * 512 * 2);
    us* WihbLo = (us*)alloc((size_t)TH3 * 512 * 2);
    float* e   = (float*)alloc(T_LEN * B_SZ * 4);
    us* cHi    = (us*)alloc(B_SZ * 512 * 2);
    us* cLo    = (us*)alloc(B_SZ * 512 * 2);
    float* gc  = (float*)alloc((size_t)B_SZ * TH3 * 4);
    float* gh  = (float*)alloc((size_t)B_SZ * TH3 * 4);
    float* gi  = (float*)alloc((size_t)B_SZ * TH3 * 4);
    float* hF[2]; us* hHi[2]; us* hLo[2];
    hF[0] = (float*)alloc(B_SZ * 512 * 4);
    hF[1] = (float*)alloc(B_SZ * 512 * 4);
    hHi[0] = (us*)alloc(B_SZ * 512 * 2);
    hHi[1] = (us*)alloc(B_SZ * 512 * 2);
    hLo[0] = (us*)alloc(B_SZ * 512 * 2);
    hLo[1] = (us*)alloc(B_SZ * 512 * 2);
    unsigned long long* slots = (unsigned long long*)alloc(2 * B_SZ * 8);
    unsigned* ctrs = (unsigned*)alloc(CTR_WORDS * 4);
    // fresh per-step packed h buffers (10.5 MB x2)
    us* hPkHi = (us*)alloc((size_t)MAXLEN * HPK_ELEMS * 2);
    us* hPkLo = (us*)alloc((size_t)MAXLEN * HPK_ELEMS * 2);
    // Wc pre-conversion (16 MB) -- must never be evicted by Egi.
    us* WcHi = (us*)alloc((size_t)CLS * 512 * 2);
    us* WcLo = (us*)alloc((size_t)CLS * 512 * 2);
    const bool PREB = (off <= ws_size);
    // Egi LAST (49 MB), self-gating.
    float* Egi = (float*)alloc((size_t)EGI_ROWS * TH3 * 4);
    const bool EGIB = (off <= ws_size);

    // prologue: weight conversions into packed fragment layout
    cvt2p_kernel<<<(512 * 128) / 256, 256, 0, stream>>>(Wq, Wk, 512, 512L * 128, WqkHi, WqkLo);
    cvt2p_kernel<<<(TH3 * 128) / 256, 256, 0, stream>>>(W_hh, nullptr, 512, (long)TH3 * 128, WhhHi, WhhLo);
    cvt2p_kernel<<<(TH3 * 128) / 256, 256, 0, stream>>>(W_ih, nullptr, 1024, (long)TH3 * 128, WihaHi, WihaLo);
    cvt2p_kernel<<<(TH3 * 128) / 256, 256, 0, stream>>>(W_ih + 512, nullptr, 1024, (long)TH3 * 128, WihbHi, WihbLo);
    if (PREB)
        cvt2p_kernel<<<(CLS * 128) / 256, 256, 0, stream>>>(Wc, nullptr, 512, (long)CLS * 128, WcHi, WcLo);
    if (EGIB)
        egi_kernel<<<8 * 6 * 500, 512, 0, stream>>>(emb, WihaHi, WihaLo, Egi);

    attn_e_mfma<<<(T_LEN * B_SZ) / 32, 256, 0, stream>>>(inp, WqkHi, WqkLo, bq, bk, v, e);
    softmax_ctx_kernel<<<B_SZ, 256, 0, stream>>>(inp, e, cHi, cLo, hF[1], hHi[1], hLo[1], slots, ctrs);
    gemm128_kernel<<<384, 512, 0, stream>>>(cHi, cLo, WihbHi, WihbLo, b_ih, gc);

    if (EGIB && PREB) {
        // gh(0) in prologue; ONE fused launch per step.
        gh_kernel<<<384, 512, 0, stream>>>(hHi[1], hLo[1], WhhHi, WhhLo, b_hh, gh);
        for (int t = 0; t < MAXLEN; ++t) {
            const int pi = (t + 1) & 1, ci = t & 1;
            fused_step_kernel<<<1408, 512, 0, stream>>>(
                WhhHi, WhhLo, b_hh, WcHi, WcLo, bc, Egi, gc, gh,
                slots + pi * B_SZ, slots + ci * B_SZ,
                hF[pi], hF[ci],
                hPkHi + (size_t)t * HPK_ELEMS, hPkLo + (size_t)t * HPK_ELEMS,
                out + (size_t)t * B_SZ * CLS, ctrs + t * 32);
        }
    } else if (EGIB) {
        gh_kernel<<<384, 512, 0, stream>>>(hHi[1], hLo[1], WhhHi, WhhLo, b_hh, gh);
        for (int t = 0; t < MAXLEN; ++t) {
            const int pi = (t + 1) & 1, ci = t & 1;
            unsigned long long* sPrev = slots + pi * B_SZ;
            unsigned long long* sCur  = slots + ci * B_SZ;
            gru_combine_egi<<<B_SZ, 512, 0, stream>>>(
                gh, Egi, gc, sPrev, hF[pi], hF[ci], hHi[ci], hLo[ci], sCur);
            cls_gh_kernel<true><<<1408, 512, 0, stream>>>(
                hHi[ci], hLo[ci], nullptr, nullptr, Wc, bc,
                out + (size_t)t * B_SZ * CLS, sCur,
                WhhHi, WhhLo, b_hh, gh);
        }
    } else {
        for (int t = 0; t < MAXLEN; ++t) {
            const int pi = (t + 1) & 1, ci = t & 1;
            unsigned long long* sPrev = slots + pi * B_SZ;
            unsigned long long* sCur  = slots + ci * B_SZ;
            step_dual_kernel<<<768, 512, 0, stream>>>(
                hHi[pi], hLo[pi], WhhHi, WhhLo, b_hh,
                emb, sPrev, WihaHi, WihaLo, gc, gh, gi);
            gru_combine<<<B_SZ, 512, 0, stream>>>(
                gh, gi, hF[pi], hF[ci], hHi[ci], hLo[ci], sCur);
            if (PREB)
                cls_kernel<false><<<1024, 512, 0, stream>>>(
                    hHi[ci], hLo[ci], WcHi, WcLo, nullptr, bc,
                    out + (size_t)t * B_SZ * CLS, sCur);
            else
                cls_kernel<true><<<1024, 512, 0, stream>>>(
                    hHi[ci], hLo[ci], nullptr, nullptr, Wc, bc,
                    out + (size_t)t * B_SZ * CLS, sCur);
        }
    }
}

// Round 9
// 2613.247 us; speedup vs baseline: 1.8205x; 1.8205x over previous
//
#include <hip/hip_runtime.h>
#include <cstdint>
#include <cstddef>

#define D_MOD 512
#define TH3   1536
#define CLS   8000
#define MAXLEN 80
#define B_SZ  128
#define T_LEN 128
#define NK0   16   // 512/32 k-chunks
#define EGI_ROWS 8000

typedef __attribute__((ext_vector_type(8))) __bf16 bf16x8;
typedef __attribute__((ext_vector_type(8))) unsigned short u16x8;
typedef __attribute__((ext_vector_type(4))) float f32x4;

// ---------------------------------------------------------------------------
// helpers
// ---------------------------------------------------------------------------
__device__ __forceinline__ unsigned short f2bf(float x) {
    unsigned u = __float_as_uint(x);
    unsigned r = ((u >> 16) & 1u) + 0x7fffu;   // RNE
    return (unsigned short)((u + r) >> 16);
}
__device__ __forceinline__ float bf2f(unsigned short h) {
    return __uint_as_float(((unsigned)h) << 16);
}
__device__ __forceinline__ f32x4 mfma16(u16x8 a, u16x8 b, f32x4 c) {
    return __builtin_amdgcn_mfma_f32_16x16x32_bf16(
        __builtin_bit_cast(bf16x8, a), __builtin_bit_cast(bf16x8, b), c, 0, 0, 0);
}
__device__ __forceinline__ void conv8(const float* __restrict__ p, u16x8& hi, u16x8& lo) {
    float4 f0 = *(const float4*)p;
    float4 f1 = *(const float4*)(p + 4);
    float fs[8] = {f0.x, f0.y, f0.z, f0.w, f1.x, f1.y, f1.z, f1.w};
    #pragma unroll
    for (int j = 0; j < 8; ++j) {
        unsigned short h = f2bf(fs[j]);
        hi[j] = h;
        lo[j] = f2bf(fs[j] - bf2f(h));
    }
}
__device__ __forceinline__ unsigned long long packkey(float v, int n) {
    unsigned u = __float_as_uint(v);
    u = (u & 0x80000000u) ? ~u : (u | 0x80000000u);
    return ((unsigned long long)u << 32) | (unsigned)(~(unsigned)n);
}
__device__ __forceinline__ unsigned long long shfl_xor_u64(unsigned long long x, int mask) {
    unsigned lo = (unsigned)x, hi = (unsigned)(x >> 32);
    lo = __shfl_xor(lo, mask, 16);
    hi = __shfl_xor(hi, mask, 16);
    return ((unsigned long long)hi << 32) | lo;
}
// fragment-major packed offset for (row n, col k), rows grouped in tiles of 16
__device__ __forceinline__ size_t pk_off(int n, int k) {
    int tile = n >> 4, lr = n & 15, k0i = k >> 5, lk = (k >> 3) & 3, e = k & 7;
    return ((size_t)(tile * NK0 + k0i) * 64 + (lk * 16 + lr)) * 8 + e;
}

// ---------------------------------------------------------------------------
// fp32 -> bf16 hi/lo PACKED converter. total4 = R*128 groups of 4 elems.
// ---------------------------------------------------------------------------
__global__ __launch_bounds__(256) void cvt2p_kernel(
    const float* __restrict__ s1, const float* __restrict__ s2, int ld,
    long total4, unsigned short* __restrict__ hi, unsigned short* __restrict__ lo)
{
    long i4 = (long)blockIdx.x * 256 + threadIdx.x;
    if (i4 >= total4) return;
    long r = i4 >> 7;
    int c = (int)(i4 & 127) * 4;
    float4 a = *(const float4*)(s1 + r * (long)ld + c);
    if (s2) {
        float4 b = *(const float4*)(s2 + r * (long)ld + c);
        a.x += b.x; a.y += b.y; a.z += b.z; a.w += b.w;
    }
    float xs[4] = {a.x, a.y, a.z, a.w};
    unsigned short hs[4], ls[4];
    #pragma unroll
    for (int j = 0; j < 4; ++j) {
        hs[j] = f2bf(xs[j]);
        ls[j] = f2bf(xs[j] - bf2f(hs[j]));
    }
    size_t o = pk_off((int)r, c);
    *(ushort4*)(hi + o) = make_ushort4(hs[0], hs[1], hs[2], hs[3]);
    *(ushort4*)(lo + o) = make_ushort4(ls[0], ls[1], ls[2], ls[3]);
}

// ---------------------------------------------------------------------------
// K-split MFMA GEMM body, 8 waves = NS n-subtiles x KS k-slices.
// Wave tile: 16 m x 32 n x (512/KS) k. LDS tree-reduce (red buffer passed in,
// needs (KS-1)*NS*576 floats). GATHER_CONV with gslot==nullptr -> direct row.
// ---------------------------------------------------------------------------
template<bool GATHER_CONV, bool CONVB, bool ADD2D, bool ARGMAX, int NS, int KS>
__device__ __forceinline__ void gemm_ks2(
    float* __restrict__ red,
    const unsigned short* __restrict__ Ahi, const unsigned short* __restrict__ Alo,
    const float* __restrict__ Afp, const unsigned long long* __restrict__ gslot,
    const unsigned short* __restrict__ Bhi, const unsigned short* __restrict__ Blo,
    const float* __restrict__ Bfp,
    const float* __restrict__ bias, const float* __restrict__ D2,
    float* __restrict__ C, int ldc,
    unsigned long long* __restrict__ aslot, int bx, int by)
{
    static_assert(NS * KS == 8, "8 waves per block");
    const int tid = threadIdx.x;
    const int w = tid >> 6, lane = tid & 63;
    const int lr = lane & 15, lk = lane >> 4;
    const int ns = w % NS, ks = w / NS;
    const int m0 = by * 16;
    const int n0 = (bx * NS + ns) * 32;
    const int tA = by;
    const int tB0 = n0 >> 4, tB1 = tB0 + 1;

    const float* paf = nullptr;
    if constexpr (GATHER_CONV) {
        int g = gslot ? (int)(~(unsigned)gslot[m0 + lr]) : (m0 + lr);
        paf = Afp + (size_t)g * D_MOD + lk * 8;
    }
    const float *pb0f = nullptr, *pb1f = nullptr;
    if constexpr (CONVB) {
        pb0f = Bfp + (size_t)(n0 + lr) * D_MOD + lk * 8;
        pb1f = Bfp + (size_t)(n0 + 16 + lr) * D_MOD + lk * 8;
    }

    f32x4 acc0 = (f32x4){0.f, 0.f, 0.f, 0.f};
    f32x4 acc1 = (f32x4){0.f, 0.f, 0.f, 0.f};

    const int kBeg = ks * (NK0 / KS), kEnd = kBeg + (NK0 / KS);
    for (int k0i = kBeg; k0i < kEnd; ++k0i) {
        u16x8 ah, al, b0h, b0l, b1h, b1l;
        if constexpr (GATHER_CONV) {
            conv8(paf + k0i * 32, ah, al);
        } else {
            size_t oA = ((size_t)(tA * NK0 + k0i) * 64 + lane) * 8;
            ah = *(const u16x8*)(Ahi + oA); al = *(const u16x8*)(Alo + oA);
        }
        if constexpr (CONVB) {
            conv8(pb0f + k0i * 32, b0h, b0l);
            conv8(pb1f + k0i * 32, b1h, b1l);
        } else {
            size_t oB0 = ((size_t)(tB0 * NK0 + k0i) * 64 + lane) * 8;
            size_t oB1 = ((size_t)(tB1 * NK0 + k0i) * 64 + lane) * 8;
            b0h = *(const u16x8*)(Bhi + oB0); b0l = *(const u16x8*)(Blo + oB0);
            b1h = *(const u16x8*)(Bhi + oB1); b1l = *(const u16x8*)(Blo + oB1);
        }
        acc0 = mfma16(ah, b0h, acc0);
        acc0 = mfma16(ah, b0l, acc0);
        acc0 = mfma16(al, b0h, acc0);
        acc1 = mfma16(ah, b1h, acc1);
        acc1 = mfma16(ah, b1l, acc1);
        acc1 = mfma16(al, b1h, acc1);
    }

    float af[8];
    #pragma unroll
    for (int i = 0; i < 4; ++i) { af[i] = acc0[i]; af[4 + i] = acc1[i]; }

    if (ks > 0) {
        const int slot = (ks - 1) * NS + ns;
        #pragma unroll
        for (int i = 0; i < 8; ++i) red[slot * 576 + lane * 9 + i] = af[i];
    }
    __syncthreads();
    if (ks == 0) {
        #pragma unroll
        for (int j = 1; j < KS; ++j) {
            const int slot = (j - 1) * NS + ns;
            #pragma unroll
            for (int i = 0; i < 8; ++i) af[i] += red[slot * 576 + lane * 9 + i];
        }
        #pragma unroll
        for (int r = 0; r < 4; ++r) {
            const int row = m0 + lk * 4 + r;
            unsigned long long kmax = 0ull;
            #pragma unroll
            for (int ni = 0; ni < 2; ++ni) {
                const int col = n0 + ni * 16 + lr;
                float val = af[ni * 4 + r];
                if (bias) val += bias[col];
                if constexpr (ADD2D) val += D2[(size_t)row * ldc + col];
                C[(size_t)row * ldc + col] = val;
                if constexpr (ARGMAX) {
                    unsigned long long k = packkey(val, col);
                    if (k > kmax) kmax = k;
                }
            }
            if constexpr (ARGMAX) {
                #pragma unroll
                for (int off = 1; off < 16; off <<= 1) {
                    unsigned long long o = shfl_xor_u64(kmax, off);
                    if (o > kmax) kmax = o;
                }
                if (lr == 0) atomicMax(&aslot[row], kmax);
            }
        }
    }
}

// XCD-pinned remap: physical block p (round-robin p%8 over XCDs) ->
// (bx, by) with all 8 by-sharers of a bx consecutive on ONE XCD.
template<int G>
__device__ __forceinline__ bool xcd_map(int p, int& bx, int& by) {
    int x = p & 7, s = p >> 3;
    by = s & 7;
    bx = x * G + (s >> 3);
    return true;
}

// ---------------------------------------------------------------------------
// one-time prologue (EGIB only): Egi = emb @ Wiha^T, rows 0..7999.
// Same gemm template as the per-step gi path -> bit-identical summation.
// ---------------------------------------------------------------------------
__global__ __launch_bounds__(512) void egi_kernel(
    const float* __restrict__ emb,
    const unsigned short* __restrict__ WihaHi, const unsigned short* __restrict__ WihaLo,
    float* __restrict__ Egi)
{
    __shared__ float red[7 * 576];
    int p = blockIdx.x;
    int x = p & 7, s = p >> 3;
    int by = s % 500, bx = x * 6 + s / 500;   // same-bx blocks pinned per XCD
    gemm_ks2<true, false, false, false, 1, 8>(red, nullptr, nullptr, emb, nullptr,
        WihaHi, WihaLo, nullptr, nullptr, nullptr, Egi, TH3, nullptr, bx, by);
}

// gh = h @ Whh^T + b_hh only, grid 384 x 512thr (prologue gh(0))
__global__ __launch_bounds__(512) void gh_kernel(
    const unsigned short* __restrict__ hHi, const unsigned short* __restrict__ hLo,
    const unsigned short* __restrict__ WhhHi, const unsigned short* __restrict__ WhhLo,
    const float* __restrict__ b_hh, float* __restrict__ gh)
{
    __shared__ float red[7 * 576];
    int bx, by;
    xcd_map<6>(blockIdx.x, bx, by);
    gemm_ks2<false, false, false, false, 1, 8>(red, hHi, hLo, nullptr, nullptr,
        WhhHi, WhhLo, nullptr, b_hh, nullptr, gh, TH3, nullptr, bx, by);
}

// ---------------------------------------------------------------------------
// MERGED step node: cls(t) [p<1024] parallel with gh(t+1) [p>=1024].
// Both depend only on h(t); no intra-kernel dependency. grid 1408 x 512thr.
// ---------------------------------------------------------------------------
template<bool CONVB>
__global__ __launch_bounds__(512) void cls_gh_kernel(
    const unsigned short* __restrict__ hHi, const unsigned short* __restrict__ hLo,
    const unsigned short* __restrict__ WcHi, const unsigned short* __restrict__ WcLo,
    const float* __restrict__ Wc, const float* __restrict__ bc,
    float* __restrict__ C, unsigned long long* __restrict__ aslot,
    const unsigned short* __restrict__ WhhHi, const unsigned short* __restrict__ WhhLo,
    const float* __restrict__ b_hh, float* __restrict__ gh)
{
    __shared__ float red[7 * 576];   // max of both paths' needs
    const int p = blockIdx.x;
    if (p < 1024) {
        int bx, by;
        xcd_map<16>(p, bx, by);
        if (bx >= 125) return;
        gemm_ks2<false, CONVB, false, true, 2, 4>(red, hHi, hLo, nullptr, nullptr,
            WcHi, WcLo, Wc, bc, nullptr, C, CLS, aslot, bx, by);
    } else {
        int bx, by;
        xcd_map<6>(p - 1024, bx, by);   // 1024 % 8 == 0 -> XCD parity preserved
        gemm_ks2<false, false, false, false, 1, 8>(red, hHi, hLo, nullptr, nullptr,
            WhhHi, WhhLo, nullptr, b_hh, nullptr, gh, TH3, nullptr, bx, by);
    }
}

// gh (p<384) and gi (p>=384), grid 768 x 512thr (fallback step node 1)
__global__ __launch_bounds__(512) void step_dual_kernel(
    const unsigned short* __restrict__ hHi, const unsigned short* __restrict__ hLo,
    const unsigned short* __restrict__ WhhHi, const unsigned short* __restrict__ WhhLo,
    const float* __restrict__ b_hh,
    const float* __restrict__ emb, const unsigned long long* __restrict__ sPrev,
    const unsigned short* __restrict__ WihaHi, const unsigned short* __restrict__ WihaLo,
    const float* __restrict__ gc,
    float* __restrict__ gh, float* __restrict__ gi)
{
    __shared__ float red[7 * 576];
    int p = blockIdx.x;
    const int z = (p >= 384);
    p -= z * 384;
    int bx, by;
    xcd_map<6>(p, bx, by);
    if (z == 0)
        gemm_ks2<false, false, false, false, 1, 8>(red, hHi, hLo, nullptr, nullptr,
            WhhHi, WhhLo, nullptr, b_hh, nullptr, gh, TH3, nullptr, bx, by);
    else
        gemm_ks2<true, false, true, false, 1, 8>(red, nullptr, nullptr, emb, sPrev,
            WihaHi, WihaLo, nullptr, nullptr, gc, gi, TH3, nullptr, bx, by);
}

// gc = c @ Wihb^T + b_ih, grid 384 x 512thr
__global__ __launch_bounds__(512) void gemm128_kernel(
    const unsigned short* __restrict__ Ahi, const unsigned short* __restrict__ Alo,
    const unsigned short* __restrict__ Bhi, const unsigned short* __restrict__ Blo,
    const float* __restrict__ bias, float* __restrict__ C)
{
    __shared__ float red[7 * 576];
    int bx, by;
    xcd_map<6>(blockIdx.x, bx, by);
    gemm_ks2<false, false, false, false, 1, 8>(red, Ahi, Alo, nullptr, nullptr,
        Bhi, Blo, nullptr, bias, nullptr, C, TH3, nullptr, bx, by);
}

// classifier standalone (fallback): grid 1024 x 512thr
template<bool CONVB>
__global__ __launch_bounds__(512) void cls_kernel(
    const unsigned short* __restrict__ hHi, const unsigned short* __restrict__ hLo,
    const unsigned short* __restrict__ WcHi, const unsigned short* __restrict__ WcLo,
    const float* __restrict__ Wc, const float* __restrict__ bc,
    float* __restrict__ C, unsigned long long* __restrict__ aslot)
{
    __shared__ float red[3 * 2 * 576];
    int bx, by;
    xcd_map<16>(blockIdx.x, bx, by);
    if (bx >= 125) return;
    gemm_ks2<false, CONVB, false, true, 2, 4>(red, hHi, hLo, nullptr, nullptr,
        WcHi, WcLo, Wc, bc, nullptr, C, CLS, aslot, bx, by);
}

// ---------------------------------------------------------------------------
// attention scores e[m] = v . tanh(inp_row @ Wqk^T + bq+bk), packed B.
// grid 512, block 256 (4 waves); wave w covers n in [w*128, w*128+128).
// ---------------------------------------------------------------------------
__global__ __launch_bounds__(256) void attn_e_mfma(
    const float* __restrict__ inp,
    const unsigned short* __restrict__ WqkHi, const unsigned short* __restrict__ WqkLo,
    const float* __restrict__ bq, const float* __restrict__ bk,
    const float* __restrict__ v, float* __restrict__ e)
{
    __shared__ __align__(16) unsigned short Ah[32][40];
    __shared__ __align__(16) unsigned short Al[32][40];
    __shared__ float red[4][32];
    const int tid = threadIdx.x, w = tid >> 6, lane = tid & 63;
    const int lr = lane & 15, lk = lane >> 4;
    const int m0 = blockIdx.x * 32;
    const int srow = tid >> 3, scol = (tid & 7) * 4;

    f32x4 acc[2][8];
    #pragma unroll
    for (int i = 0; i < 2; ++i)
        #pragma unroll
        for (int j = 0; j < 8; ++j) acc[i][j] = (f32x4){0.f, 0.f, 0.f, 0.f};

    for (int k0i = 0; k0i < NK0; ++k0i) {
        float4 x = *(const float4*)(inp + (size_t)(m0 + srow) * D_MOD + k0i * 32 + scol);
        float xs[4] = {x.x, x.y, x.z, x.w};
        #pragma unroll
        for (int j = 0; j < 4; ++j) {
            unsigned short h = f2bf(xs[j]);
            Ah[srow][scol + j] = h;
            Al[srow][scol + j] = f2bf(xs[j] - bf2f(h));
        }
        __syncthreads();
        u16x8 a[2][2];
        #pragma unroll
        for (int mi = 0; mi < 2; ++mi) {
            a[mi][0] = *(const u16x8*)&Ah[mi * 16 + lr][lk * 8];
            a[mi][1] = *(const u16x8*)&Al[mi * 16 + lr][lk * 8];
        }
        #pragma unroll
        for (int nf = 0; nf < 8; ++nf) {
            const int tile = w * 8 + nf;
            size_t ob = ((size_t)(tile * NK0 + k0i) * 64 + lane) * 8;
            u16x8 bh = *(const u16x8*)(WqkHi + ob);
            u16x8 bl = *(const u16x8*)(WqkLo + ob);
            #pragma unroll
            for (int mi = 0; mi < 2; ++mi) {
                acc[mi][nf] = mfma16(a[mi][0], bh, acc[mi][nf]);
                acc[mi][nf] = mfma16(a[mi][0], bl, acc[mi][nf]);
                acc[mi][nf] = mfma16(a[mi][1], bh, acc[mi][nf]);
            }
        }
        __syncthreads();
    }

    float ep[2][4];
    #pragma unroll
    for (int mi = 0; mi < 2; ++mi)
        #pragma unroll
        for (int r = 0; r < 4; ++r) ep[mi][r] = 0.f;
    #pragma unroll
    for (int nf = 0; nf < 8; ++nf) {
        const int col = w * 128 + nf * 16 + lr;
        const float bb = bq[col] + bk[col];
        const float vv = v[col];
        #pragma unroll
        for (int mi = 0; mi < 2; ++mi)
            #pragma unroll
            for (int r = 0; r < 4; ++r)
                ep[mi][r] += vv * tanhf(acc[mi][nf][r] + bb);
    }
    #pragma unroll
    for (int mi = 0; mi < 2; ++mi)
        #pragma unroll
        for (int r = 0; r < 4; ++r) {
            float s = ep[mi][r];
            #pragma unroll
            for (int off = 1; off < 16; off <<= 1) s += __shfl_xor(s, off, 16);
            if (lr == 0) red[w][mi * 16 + lk * 4 + r] = s;
        }
    __syncthreads();
    if (tid < 32) e[m0 + tid] = red[0][tid] + red[1][tid] + red[2][tid] + red[3][tid];
}

// ---------------------------------------------------------------------------
// softmax over T per batch col; context c and h0 emitted PACKED hi/lo;
// h0 also fp32 row-major; slot init. grid 128, block 256.
// ---------------------------------------------------------------------------
__global__ __launch_bounds__(256) void softmax_ctx_kernel(
    const float* __restrict__ inp, const float* __restrict__ e,
    unsigned short* __restrict__ cHi, unsigned short* __restrict__ cLo,
    float* __restrict__ h1, unsigned short* __restrict__ h1Hi, unsigned short* __restrict__ h1Lo,
    unsigned long long* __restrict__ slots)
{
    __shared__ float att[T_LEN];
    __shared__ float red;
    const int b = blockIdx.x, tid = threadIdx.x;
    float val = -1e30f;
    if (tid < T_LEN) { val = e[(size_t)tid * B_SZ + b]; att[tid] = val; }
    __syncthreads();
    if (tid < 64) {
        float m = fmaxf(att[tid], att[tid + 64]);
        #pragma unroll
        for (int off = 32; off; off >>= 1) m = fmaxf(m, __shfl_xor(m, off));
        if (tid == 0) red = m;
    }
    __syncthreads();
    const float mx = red;
    __syncthreads();
    if (tid < T_LEN) att[tid] = expf(val - mx);
    __syncthreads();
    if (tid < 64) {
        float s = att[tid] + att[tid + 64];
        #pragma unroll
        for (int off = 32; off; off >>= 1) s += __shfl_xor(s, off);
        if (tid == 0) red = s;
    }
    __syncthreads();
    const float inv = 1.f / red;

    const int d0 = tid * 2;
    float ax = 0.f, ay = 0.f;
    for (int t = 0; t < T_LEN; ++t) {
        float a = att[t];
        float2 x = *(const float2*)(inp + ((size_t)t * B_SZ + b) * D_MOD + d0);
        ax += a * x.x; ay += a * x.y;
        if (t == 0) {
            *(float2*)(h1 + (size_t)b * D_MOD + d0) = x;
            unsigned short hx = f2bf(x.x), hy = f2bf(x.y);
            h1Hi[pk_off(b, d0)]     = hx;
            h1Hi[pk_off(b, d0 + 1)] = hy;
            h1Lo[pk_off(b, d0)]     = f2bf(x.x - bf2f(hx));
            h1Lo[pk_off(b, d0 + 1)] = f2bf(x.y - bf2f(hy));
        }
    }
    ax *= inv; ay *= inv;
    unsigned short cx = f2bf(ax), cy = f2bf(ay);
    cHi[pk_off(b, d0)]     = cx;
    cHi[pk_off(b, d0 + 1)] = cy;
    cLo[pk_off(b, d0)]     = f2bf(ax - bf2f(cx));
    cLo[pk_off(b, d0 + 1)] = f2bf(ay - bf2f(cy));
    if (tid == 0) {
        slots[b] = 0ull;
        slots[B_SZ + b] = 0x00000000FFFFFFFFull;   // idx 0 (SOS)
    }
}

// ---------------------------------------------------------------------------
// GRU combine (fallback): reads per-step gi buffer. grid 128, block 512.
// ---------------------------------------------------------------------------
__global__ __launch_bounds__(512) void gru_combine(
    const float* __restrict__ gh, const float* __restrict__ gi,
    const float* __restrict__ hPrev, float* __restrict__ hCur,
    unsigned short* __restrict__ hHiC, unsigned short* __restrict__ hLoC,
    unsigned long long* __restrict__ slotCur)
{
    const int b = blockIdx.x, k = threadIdx.x;
    const float* gib = gi + (size_t)b * TH3;
    const float* ghb = gh + (size_t)b * TH3;
    float r = 1.f / (1.f + expf(-(gib[k] + ghb[k])));
    float z = 1.f / (1.f + expf(-(gib[k + 512] + ghb[k + 512])));
    float n = tanhf(gib[k + 1024] + r * ghb[k + 1024]);
    float h = hPrev[(size_t)b * D_MOD + k];
    float hv = (1.f - z) * n + z * h;
    hCur[(size_t)b * D_MOD + k] = hv;
    unsigned short hh = f2bf(hv);
    size_t o = pk_off(b, k);
    hHiC[o] = hh;
    hLoC[o] = f2bf(hv - bf2f(hh));
    if (k == 0) slotCur[b] = 0ull;
}

// ---------------------------------------------------------------------------
// GRU combine (EGIB): gi = Egi[sel] + gc gather, identical fp32 add order
// to the fallback's (gemm + gc) then + gh. grid 128, block 512.
// ---------------------------------------------------------------------------
__global__ __launch_bounds__(512) void gru_combine_egi(
    const float* __restrict__ gh, const float* __restrict__ Egi,
    const float* __restrict__ gc, const unsigned long long* __restrict__ sPrev,
    const float* __restrict__ hPrev, float* __restrict__ hCur,
    unsigned short* __restrict__ hHiC, unsigned short* __restrict__ hLoC,
    unsigned long long* __restrict__ slotCur)
{
    const int b = blockIdx.x, k = threadIdx.x;
    const int sel = (int)(~(unsigned)sPrev[b]);
    const float* gib = Egi + (size_t)sel * TH3;
    const float* gcb = gc + (size_t)b * TH3;
    const float* ghb = gh + (size_t)b * TH3;
    float gi0 = gib[k] + gcb[k];
    float gi1 = gib[k + 512] + gcb[k + 512];
    float gi2 = gib[k + 1024] + gcb[k + 1024];
    float r = 1.f / (1.f + expf(-(gi0 + ghb[k])));
    float z = 1.f / (1.f + expf(-(gi1 + ghb[k + 512])));
    float n = tanhf(gi2 + r * ghb[k + 1024]);
    float h = hPrev[(size_t)b * D_MOD + k];
    float hv = (1.f - z) * n + z * h;
    hCur[(size_t)b * D_MOD + k] = hv;
    unsigned short hh = f2bf(hv);
    size_t o = pk_off(b, k);
    hHiC[o] = hh;
    hLoC[o] = f2bf(hv - bf2f(hh));
    if (k == 0) slotCur[b] = 0ull;
}

// ---------------------------------------------------------------------------
// launch
// ---------------------------------------------------------------------------
extern "C" void kernel_launch(void* const* d_in, const int* in_sizes, int n_in,
                              void* d_out, int out_size, void* d_ws, size_t ws_size,
                              hipStream_t stream)
{
    const float* inp  = (const float*)d_in[0];
    const float* Wq   = (const float*)d_in[1];
    const float* bq   = (const float*)d_in[2];
    const float* Wk   = (const float*)d_in[3];
    const float* bk   = (const float*)d_in[4];
    const float* v    = (const float*)d_in[5];
    const float* W_ih = (const float*)d_in[6];
    const float* b_ih = (const float*)d_in[7];
    const float* W_hh = (const float*)d_in[8];
    const float* b_hh = (const float*)d_in[9];
    const float* emb  = (const float*)d_in[10];
    const float* Wc   = (const float*)d_in[11];
    const float* bc   = (const float*)d_in[12];
    float* out = (float*)d_out;

    char* base = (char*)d_ws;
    size_t off = 0;
    auto alloc = [&](size_t bytes) -> char* {
        char* q = base + off;
        off += (bytes + 255) & ~(size_t)255;
        return q;
    };
    typedef unsigned short us;
    us* WqkHi  = (us*)alloc(512 * 512 * 2);
    us* WqkLo  = (us*)alloc(512 * 512 * 2);
    us* WhhHi  = (us*)alloc((size_t)TH3 * 512 * 2);
    us* WhhLo  = (us*)alloc((size_t)TH3 * 512 * 2);
    us* WihaHi = (us*)alloc((size_t)TH3 * 512 * 2);
    us* WihaLo = (us*)alloc((size_t)TH3 * 512 * 2);
    us* WihbHi = (us*)alloc((size_t)TH3 * 512 * 2);
    us* WihbLo = (us*)alloc((size_t)TH3 * 512 * 2);
    float* e   = (float*)alloc(T_LEN * B_SZ * 4);
    us* cHi    = (us*)alloc(B_SZ * 512 * 2);
    us* cLo    = (us*)alloc(B_SZ * 512 * 2);
    float* gc  = (float*)alloc((size_t)B_SZ * TH3 * 4);
    float* gh  = (float*)alloc((size_t)B_SZ * TH3 * 4);
    float* gi  = (float*)alloc((size_t)B_SZ * TH3 * 4);
    float* hF[2]; us* hHi[2]; us* hLo[2];
    hF[0] = (float*)alloc(B_SZ * 512 * 4);
    hF[1] = (float*)alloc(B_SZ * 512 * 4);
    hHi[0] = (us*)alloc(B_SZ * 512 * 2);
    hHi[1] = (us*)alloc(B_SZ * 512 * 2);
    hLo[0] = (us*)alloc(B_SZ * 512 * 2);
    hLo[1] = (us*)alloc(B_SZ * 512 * 2);
    unsigned long long* slots = (unsigned long long*)alloc(2 * B_SZ * 8);
    // Wc pre-conversion FIRST (16 MB) -- must never be evicted by Egi.
    us* WcHi = (us*)alloc((size_t)CLS * 512 * 2);
    us* WcLo = (us*)alloc((size_t)CLS * 512 * 2);
    const bool PREB = (off <= ws_size);
    // Egi LAST (49 MB), self-gating.
    float* Egi = (float*)alloc((size_t)EGI_ROWS * TH3 * 4);
    const bool EGIB = (off <= ws_size);

    // prologue: weight conversions into packed fragment layout
    cvt2p_kernel<<<(512 * 128) / 256, 256, 0, stream>>>(Wq, Wk, 512, 512L * 128, WqkHi, WqkLo);
    cvt2p_kernel<<<(TH3 * 128) / 256, 256, 0, stream>>>(W_hh, nullptr, 512, (long)TH3 * 128, WhhHi, WhhLo);
    cvt2p_kernel<<<(TH3 * 128) / 256, 256, 0, stream>>>(W_ih, nullptr, 1024, (long)TH3 * 128, WihaHi, WihaLo);
    cvt2p_kernel<<<(TH3 * 128) / 256, 256, 0, stream>>>(W_ih + 512, nullptr, 1024, (long)TH3 * 128, WihbHi, WihbLo);
    if (PREB)
        cvt2p_kernel<<<(CLS * 128) / 256, 256, 0, stream>>>(Wc, nullptr, 512, (long)CLS * 128, WcHi, WcLo);
    if (EGIB)
        egi_kernel<<<8 * 6 * 500, 512, 0, stream>>>(emb, WihaHi, WihaLo, Egi);

    attn_e_mfma<<<(T_LEN * B_SZ) / 32, 256, 0, stream>>>(inp, WqkHi, WqkLo, bq, bk, v, e);
    softmax_ctx_kernel<<<B_SZ, 256, 0, stream>>>(inp, e, cHi, cLo, hF[1], hHi[1], hLo[1], slots);
    gemm128_kernel<<<384, 512, 0, stream>>>(cHi, cLo, WihbHi, WihbLo, b_ih, gc);

    if (EGIB) {
        // gh(0) in prologue; each step is then [gru(t)] -> [cls(t) || gh(t+1)]
        gh_kernel<<<384, 512, 0, stream>>>(hHi[1], hLo[1], WhhHi, WhhLo, b_hh, gh);
        for (int t = 0; t < MAXLEN; ++t) {
            const int pi = (t + 1) & 1, ci = t & 1;
            unsigned long long* sPrev = slots + pi * B_SZ;
            unsigned long long* sCur  = slots + ci * B_SZ;

            gru_combine_egi<<<B_SZ, 512, 0, stream>>>(
                gh, Egi, gc, sPrev, hF[pi], hF[ci], hHi[ci], hLo[ci], sCur);
            if (PREB)
                cls_gh_kernel<false><<<1408, 512, 0, stream>>>(
                    hHi[ci], hLo[ci], WcHi, WcLo, nullptr, bc,
                    out + (size_t)t * B_SZ * CLS, sCur,
                    WhhHi, WhhLo, b_hh, gh);
            else
                cls_gh_kernel<true><<<1408, 512, 0, stream>>>(
                    hHi[ci], hLo[ci], nullptr, nullptr, Wc, bc,
                    out + (size_t)t * B_SZ * CLS, sCur,
                    WhhHi, WhhLo, b_hh, gh);
        }
    } else {
        for (int t = 0; t < MAXLEN; ++t) {
            const int pi = (t + 1) & 1, ci = t & 1;
            unsigned long long* sPrev = slots + pi * B_SZ;
            unsigned long long* sCur  = slots + ci * B_SZ;

            step_dual_kernel<<<768, 512, 0, stream>>>(
                hHi[pi], hLo[pi], WhhHi, WhhLo, b_hh,
                emb, sPrev, WihaHi, WihaLo, gc, gh, gi);
            gru_combine<<<B_SZ, 512, 0, stream>>>(
                gh, gi, hF[pi], hF[ci], hHi[ci], hLo[ci], sCur);
            if (PREB)
                cls_kernel<false><<<1024, 512, 0, stream>>>(
                    hHi[ci], hLo[ci], WcHi, WcLo, nullptr, bc,
                    out + (size_t)t * B_SZ * CLS, sCur);
            else
                cls_kernel<true><<<1024, 512, 0, stream>>>(
                    hHi[ci], hLo[ci], nullptr, nullptr, Wc, bc,
                    out + (size_t)t * B_SZ * CLS, sCur);
        }
    }
}